// Round 3
// baseline (5118.101 us; speedup 1.0000x reference)
//
#include <hip/hip_runtime.h>

typedef unsigned short u16;
typedef __attribute__((ext_vector_type(8))) short bf16x8;   // 8 bf16 = 4 VGPRs
typedef __attribute__((ext_vector_type(4))) float f32x4;

__device__ __forceinline__ float bf2f(u16 u) {
    union { unsigned i; float f; } v; v.i = ((unsigned)u) << 16; return v.f;
}
__device__ __forceinline__ u16 f2bf(float f) {
    union { float f; unsigned i; } v; v.f = f;
    unsigned r = v.i + 0x7FFFu + ((v.i >> 16) & 1u);   // RNE
    return (u16)(r >> 16);
}

// ---------------------------------------------------------------------------
// GEMM: C[M,N] = A[M,K] @ B[K,N], B given as B^T [N][K] bf16 (row-major, ldb).
// A is fp32 (AFP32=1, converted during staging) or bf16 (AFP32=0).
// BM=BN=128, BK=64, 256 threads = 4 waves (2x2), wave tile 64x64 = 4x4 MFMA.
// Plain staging this round (vector global load + ds_write) — no GL2LDS.
// Epilogues: 0 = +bias (fp32 aux), write transposed bf16 [N][ldout]
//            1 = relu, write normal bf16 [M][ldout]
//            3 = appnp blend: out_T = bf16(0.9*acc + 0.1*aux_T bf16)
// ---------------------------------------------------------------------------
template<int EPI, int AFP32>
__global__ __launch_bounds__(256, 2)
void gemm_bt(const void* __restrict__ Ap, int lda,
             const u16* __restrict__ Bt, int ldb,
             int KB,                       // K-iterations (of 64)
             void* __restrict__ outp,
             const void* __restrict__ aux, // fp32 bias (EPI=0) / bf16 z0T (EPI=3)
             int ldout)
{
    __shared__ u16 aL[128 * 64];          // 16 KB A tile (bf16)
    __shared__ u16 bL[128 * 64];          // 16 KB B^T tile (bf16)

    const int t = threadIdx.x;
    const int wid = t >> 6, lane = t & 63;
    const int quad = lane >> 4, l15 = lane & 15;
    const int m0 = blockIdx.x * 128, n0 = blockIdx.y * 128;

    f32x4 acc[4][4];
    const f32x4 z4 = {0.f, 0.f, 0.f, 0.f};
#pragma unroll
    for (int i = 0; i < 4; ++i)
#pragma unroll
        for (int j = 0; j < 4; ++j) acc[i][j] = z4;

    const int wm = (wid >> 1) * 64, wn = (wid & 1) * 64;

    for (int kb = 0; kb < KB; ++kb) {
        // ---- B^T staging: bf16, 4 x 16B per thread ----
#pragma unroll
        for (int i = 0; i < 4; ++i) {
            int flat = i * 4096 + t * 16;          // byte index in 16KB tile
            int row  = flat >> 7;                  // 128 B per row (64 bf16)
            int col  = (flat & 127) >> 1;          // u16 index in row
            bf16x8 v = *(const bf16x8*)(Bt + (size_t)(n0 + row) * ldb + kb * 64 + col);
            *(bf16x8*)(bL + row * 64 + col) = v;
        }
        // ---- A staging ----
        if (AFP32) {
            const float* Af = (const float*)Ap;
#pragma unroll
            for (int j = 0; j < 8; ++j) {
                int f = j * 256 + t;               // float4 index in [128][16]
                int r = f >> 4, c = (f & 15) * 4;  // c in floats
                float4 v = *(const float4*)(Af + (size_t)(m0 + r) * lda + kb * 64 + c);
                ushort4 o;
                o.x = f2bf(v.x); o.y = f2bf(v.y);
                o.z = f2bf(v.z); o.w = f2bf(v.w);
                *(ushort4*)(aL + r * 64 + c) = o;
            }
        } else {
            const u16* Ab = (const u16*)Ap;
#pragma unroll
            for (int i = 0; i < 4; ++i) {
                int flat = i * 4096 + t * 16;
                int row  = flat >> 7;
                int col  = (flat & 127) >> 1;
                bf16x8 v = *(const bf16x8*)(Ab + (size_t)(m0 + row) * lda + kb * 64 + col);
                *(bf16x8*)(aL + row * 64 + col) = v;
            }
        }
        __syncthreads();
#pragma unroll
        for (int ks = 0; ks < 2; ++ks) {
            const int cr = (ks * 4 + quad) * 8;    // k-chunk (8 elems) for quad
            bf16x8 av[4], bv[4];
#pragma unroll
            for (int mi = 0; mi < 4; ++mi)
                av[mi] = *(const bf16x8*)(aL + (wm + mi * 16 + l15) * 64 + cr);
#pragma unroll
            for (int ni = 0; ni < 4; ++ni)
                bv[ni] = *(const bf16x8*)(bL + (wn + ni * 16 + l15) * 64 + cr);
#pragma unroll
            for (int mi = 0; mi < 4; ++mi)
#pragma unroll
                for (int ni = 0; ni < 4; ++ni)
                    acc[mi][ni] = __builtin_amdgcn_mfma_f32_16x16x32_bf16(
                        av[mi], bv[ni], acc[mi][ni], 0, 0, 0);
        }
        __syncthreads();
    }

    // Epilogue. C/D layout: n = lane&15 (col), m = quad*4 + r (row) [m89/m91].
    if (EPI == 0) {            // +bias(fp32), transposed bf16 out [N][ldout]
#pragma unroll
        for (int ni = 0; ni < 4; ++ni) {
            int n = n0 + wn + ni * 16 + l15;
            float bvv = ((const float*)aux)[n];
            u16* ob = (u16*)outp + (size_t)n * ldout;
#pragma unroll
            for (int mi = 0; mi < 4; ++mi) {
                int m = m0 + wm + mi * 16 + quad * 4;
                ushort4 o;
                o.x = f2bf(acc[mi][ni][0] + bvv);
                o.y = f2bf(acc[mi][ni][1] + bvv);
                o.z = f2bf(acc[mi][ni][2] + bvv);
                o.w = f2bf(acc[mi][ni][3] + bvv);
                *(ushort4*)(ob + m) = o;
            }
        }
    } else if (EPI == 3) {     // z_new_T = bf16(0.9*acc + 0.1*z0T)
#pragma unroll
        for (int ni = 0; ni < 4; ++ni) {
            int n = n0 + wn + ni * 16 + l15;
            const u16* zrow = (const u16*)aux + (size_t)n * 8192;
            u16* ob = (u16*)outp + (size_t)n * ldout;
#pragma unroll
            for (int mi = 0; mi < 4; ++mi) {
                int m = m0 + wm + mi * 16 + quad * 4;
                ushort4 z0 = *(const ushort4*)(zrow + m);
                ushort4 o;
                o.x = f2bf(0.9f * acc[mi][ni][0] + 0.1f * bf2f(z0.x));
                o.y = f2bf(0.9f * acc[mi][ni][1] + 0.1f * bf2f(z0.y));
                o.z = f2bf(0.9f * acc[mi][ni][2] + 0.1f * bf2f(z0.z));
                o.w = f2bf(0.9f * acc[mi][ni][3] + 0.1f * bf2f(z0.w));
                *(ushort4*)(ob + m) = o;
            }
        }
    } else {                   // relu, normal bf16 out [M][ldout]
        u16* ob = (u16*)outp;
#pragma unroll
        for (int mi = 0; mi < 4; ++mi) {
            int m = m0 + wm + mi * 16 + quad * 4;
#pragma unroll
            for (int ni = 0; ni < 4; ++ni) {
                int n = n0 + wn + ni * 16 + l15;
#pragma unroll
                for (int r = 0; r < 4; ++r)
                    ob[(size_t)(m + r) * ldout + n] = f2bf(fmaxf(acc[mi][ni][r], 0.0f));
            }
        }
    }
}

// ---------------------------------------------------------------------------
// weight transpose+convert: in fp32 [R][C] -> out bf16 [C][R]
// ---------------------------------------------------------------------------
__global__ __launch_bounds__(256)
void transpose_cvt_k(const float* __restrict__ in, u16* __restrict__ out,
                     int R, int C)
{
    __shared__ u16 tile[32][33];
    int tx = threadIdx.x, ty = threadIdx.y;
    int x = blockIdx.x * 32 + tx;
    int y0 = blockIdx.y * 32 + ty;
#pragma unroll
    for (int j = 0; j < 32; j += 8)
        tile[ty + j][tx] = f2bf(in[(size_t)(y0 + j) * C + x]);
    __syncthreads();
    int x2 = blockIdx.y * 32 + tx;
    int y2 = blockIdx.x * 32 + ty;
#pragma unroll
    for (int j = 0; j < 32; j += 8)
        out[(size_t)(y2 + j) * R + x2] = tile[tx][ty + j];
}

// ---------------------------------------------------------------------------
// softmax over channels: zT [256][8192] bf16 -> out fp32 [8192][256]
// ---------------------------------------------------------------------------
__global__ __launch_bounds__(256)
void softmax_k(const u16* __restrict__ zT, float* __restrict__ out)
{
    __shared__ u16 L[64][260];            // 260: keeps ushort4 rows 8B-aligned
    const int t = threadIdx.x;
    const int m0 = blockIdx.x * 64;
    const int tx = t & 15, ty = t >> 4;
#pragma unroll
    for (int i = 0; i < 16; ++i) {
        int n = i * 16 + ty;
        ushort4 v = *(const ushort4*)(zT + (size_t)n * 8192 + m0 + tx * 4);
        L[tx * 4 + 0][n] = v.x; L[tx * 4 + 1][n] = v.y;
        L[tx * 4 + 2][n] = v.z; L[tx * 4 + 3][n] = v.w;
    }
    __syncthreads();
    const int wid = t >> 6, lane = t & 63;
    for (int r = 0; r < 16; ++r) {
        int mm = wid * 16 + r;
        ushort4 u = *(const ushort4*)(&L[mm][lane * 4]);
        float f0 = bf2f(u.x), f1 = bf2f(u.y), f2 = bf2f(u.z), f3 = bf2f(u.w);
        float mx = fmaxf(fmaxf(f0, f1), fmaxf(f2, f3));
#pragma unroll
        for (int off = 32; off > 0; off >>= 1) mx = fmaxf(mx, __shfl_xor(mx, off));
        float e0 = __expf(f0 - mx), e1 = __expf(f1 - mx);
        float e2 = __expf(f2 - mx), e3 = __expf(f3 - mx);
        float s = e0 + e1 + e2 + e3;
#pragma unroll
        for (int off = 32; off > 0; off >>= 1) s += __shfl_xor(s, off);
        float inv = 1.0f / s;
        float4 o;
        o.x = e0 * inv; o.y = e1 * inv; o.z = e2 * inv; o.w = e3 * inv;
        *(float4*)(out + (size_t)(m0 + mm) * 256 + lane * 4) = o;
    }
}

// ---------------------------------------------------------------------------
extern "C" void kernel_launch(void* const* d_in, const int* in_sizes, int n_in,
                              void* d_out, int out_size, void* d_ws, size_t ws_size,
                              hipStream_t stream)
{
    // Inputs are fp32 per the reference file.
    const float* features = (const float*)d_in[0];   // [8192][512]
    const float* fltr     = (const float*)d_in[1];   // [8192][8192]
    const float* W0       = (const float*)d_in[2];   // [512][512]
    const float* b0       = (const float*)d_in[3];   // [512]
    const float* W1       = (const float*)d_in[4];   // [512][512]
    const float* b1       = (const float*)d_in[5];   // [512]
    const float* Wo       = (const float*)d_in[6];   // [512][256]
    const float* bo       = (const float*)d_in[7];   // [256]

    // ws layout (21.25 MB total), all bf16:
    //   W0T 512K | W1T 512K | WoT 256K | z0T 4M | region B 16M
    //   region B overlays: {tT 8M + y 8M} (MLP stage) vs {zA 4M + zB 4M} (iters)
    char* ws = (char*)d_ws;
    u16* W0T = (u16*)ws;                 ws += (size_t)512 * 512 * 2;
    u16* W1T = (u16*)ws;                 ws += (size_t)512 * 512 * 2;
    u16* WoT = (u16*)ws;                 ws += (size_t)256 * 512 * 2;
    u16* z0T = (u16*)ws;                 ws += (size_t)256 * 8192 * 2;
    char* rb = ws;
    u16* tT = (u16*)rb;                                   // [512][8192]
    u16* y  = (u16*)(rb + (size_t)512 * 8192 * 2);        // [8192][512]
    u16* zA = (u16*)rb;                                   // [256][8192]
    u16* zB = (u16*)(rb + (size_t)256 * 8192 * 2);        // [256][8192]

    dim3 tb(32, 8);
    transpose_cvt_k<<<dim3(16, 16), tb, 0, stream>>>(W0, W0T, 512, 512);
    transpose_cvt_k<<<dim3(16, 16), tb, 0, stream>>>(W1, W1T, 512, 512);
    transpose_cvt_k<<<dim3(8, 16),  tb, 0, stream>>>(Wo, WoT, 512, 256);

    // t0_T = (features @ W0 + b0)^T        A fp32, bias fp32
    gemm_bt<0, 1><<<dim3(64, 4), 256, 0, stream>>>(features, 512, W0T, 512, 8,
                                                   tT, b0, 8192);
    // y1 = relu(fltr @ t0)                 A fp32
    gemm_bt<1, 1><<<dim3(64, 4), 256, 0, stream>>>(fltr, 8192, tT, 8192, 128,
                                                   y, nullptr, 512);
    // t1_T = (y1 @ W1 + b1)^T              A bf16
    gemm_bt<0, 0><<<dim3(64, 4), 256, 0, stream>>>(y, 512, W1T, 512, 8,
                                                   tT, b1, 8192);
    // y2 = relu(fltr @ t1)                 A fp32
    gemm_bt<1, 1><<<dim3(64, 4), 256, 0, stream>>>(fltr, 8192, tT, 8192, 128,
                                                   y, nullptr, 512);
    // z0_T = (y2 @ Wo + bo)^T              A bf16
    gemm_bt<0, 0><<<dim3(64, 2), 256, 0, stream>>>(y, 512, WoT, 512, 8,
                                                   z0T, bo, 8192);

    // 10x: z <- 0.9 * fltr @ z + 0.1 * z0  A fp32, fused epilogue
    const u16* src = z0T;
    for (int it = 0; it < 10; ++it) {
        u16* dst = (it & 1) ? zB : zA;
        gemm_bt<3, 1><<<dim3(64, 2), 256, 0, stream>>>(fltr, 8192, src, 8192, 128,
                                                       dst, z0T, 8192);
        src = dst;
    }

    softmax_k<<<128, 256, 0, stream>>>(src, (float*)d_out);
}

// Round 4
// 1268.772 us; speedup vs baseline: 4.0339x; 4.0339x over previous
//
#include <hip/hip_runtime.h>

typedef unsigned short u16;
typedef __attribute__((ext_vector_type(8))) short bf16x8;   // 8 bf16 = 4 VGPRs
typedef __attribute__((ext_vector_type(4))) float f32x4;

__device__ __forceinline__ float bf2f(u16 u) {
    union { unsigned i; float f; } v; v.i = ((unsigned)u) << 16; return v.f;
}
__device__ __forceinline__ u16 f2bf(float f) {
    union { float f; unsigned i; } v; v.f = f;
    unsigned r = v.i + 0x7FFFu + ((v.i >> 16) & 1u);   // RNE
    return (u16)(r >> 16);
}

#define GL2LDS(g, l) __builtin_amdgcn_global_load_lds(                         \
    (const __attribute__((address_space(1))) void*)(g),                        \
    (__attribute__((address_space(3))) void*)(l), 16, 0, 0)

// ---------------------------------------------------------------------------
// GEMM: C[M,N] = A[M,K] @ B[K,N], B given as B^T [N][K] bf16 (row-major, ldb).
// AFP32=1: A fp32, converted during staging (manual loads).
// AFP32=0: A bf16, GL2LDS width-16 staging for both A and B (m97 pattern).
// BM=BN=128, BK=64, 256 thr = 4 waves (2x2), wave tile 64x64 = 4x4 MFMA.
// blockIdx.z = split-K index (k0 = z * KB * 64).
// Epilogues: 0 = +bias (fp32 aux), transposed bf16 out [N][ldout]
//            1 = relu, normal bf16 out [M][ldout]
//            2 = fp32 partial, transposed [sk][NC][8192]
//            3 = appnp blend: out_T = bf16(0.9*acc + 0.1*aux bf16 [N][8192])
// ---------------------------------------------------------------------------
template<int EPI, int AFP32>
__global__ __launch_bounds__(256, 4)
void gemm_bt(const void* __restrict__ Ap, int lda,
             const u16* __restrict__ Bt, int ldb,
             int KB,                        // K-iterations (of 64) per split
             void* __restrict__ outp,
             const void* __restrict__ aux,  // fp32 bias (0) / bf16 z0T (3)
             int ldout, int NC)
{
    __shared__ u16 aL[128 * 64];           // 16 KB A tile (bf16)
    __shared__ u16 bL[128 * 64];           // 16 KB B^T tile (bf16)

    const int t = threadIdx.x;
    const int wid = t >> 6, lane = t & 63;
    const int quad = lane >> 4, l15 = lane & 15;
    const int m0 = blockIdx.x * 128, n0 = blockIdx.y * 128;
    const int sk = blockIdx.z;
    const int k0 = sk * KB * 64;           // elements

    f32x4 acc[4][4];
    const f32x4 z4 = {0.f, 0.f, 0.f, 0.f};
#pragma unroll
    for (int i = 0; i < 4; ++i)
#pragma unroll
        for (int j = 0; j < 4; ++j) acc[i][j] = z4;

    const int wm = (wid >> 1) * 64, wn = (wid & 1) * 64;

    if (AFP32 == 0) {
        // ---- GL2LDS staging path (A and B both bf16) ----
        const char* pa[4]; const char* pb[4]; int lo[4];
#pragma unroll
        for (int i = 0; i < 4; ++i) {
            int flat = i * 4096 + wid * 1024 + lane * 16;  // byte in 16KB tile
            int row  = flat >> 7;                          // 128 B per row
            int col  = flat & 127;
            pa[i] = (const char*)Ap + ((size_t)(m0 + row) * lda + k0) * 2 + col;
            pb[i] = (const char*)Bt + ((size_t)(n0 + row) * ldb + k0) * 2 + col;
            lo[i] = i * 4096 + wid * 1024;                 // wave-uniform base
        }
        for (int kb = 0; kb < KB; ++kb) {
#pragma unroll
            for (int i = 0; i < 4; ++i) GL2LDS(pa[i], (char*)aL + lo[i]);
#pragma unroll
            for (int i = 0; i < 4; ++i) GL2LDS(pb[i], (char*)bL + lo[i]);
#pragma unroll
            for (int i = 0; i < 4; ++i) { pa[i] += 128; pb[i] += 128; }
            __syncthreads();               // vmcnt(0) drain before barrier
#pragma unroll
            for (int ks = 0; ks < 2; ++ks) {
                const int cr = (ks * 4 + quad) * 8;
                bf16x8 av[4], bv[4];
#pragma unroll
                for (int mi = 0; mi < 4; ++mi)
                    av[mi] = *(const bf16x8*)(aL + (wm + mi * 16 + l15) * 64 + cr);
#pragma unroll
                for (int ni = 0; ni < 4; ++ni)
                    bv[ni] = *(const bf16x8*)(bL + (wn + ni * 16 + l15) * 64 + cr);
#pragma unroll
                for (int mi = 0; mi < 4; ++mi)
#pragma unroll
                    for (int ni = 0; ni < 4; ++ni)
                        acc[mi][ni] = __builtin_amdgcn_mfma_f32_16x16x32_bf16(
                            av[mi], bv[ni], acc[mi][ni], 0, 0, 0);
            }
            __syncthreads();
        }
    } else {
        // ---- manual staging path (A fp32 -> bf16 cvt, B bf16) ----
        for (int kb = 0; kb < KB; ++kb) {
            const int kbase = k0 + kb * 64;
#pragma unroll
            for (int i = 0; i < 4; ++i) {
                int flat = i * 4096 + t * 16;
                int row  = flat >> 7;
                int col  = (flat & 127) >> 1;
                bf16x8 v = *(const bf16x8*)(Bt + (size_t)(n0 + row) * ldb + kbase + col);
                *(bf16x8*)(bL + row * 64 + col) = v;
            }
            const float* Af = (const float*)Ap;
#pragma unroll
            for (int j = 0; j < 8; ++j) {
                int f = j * 256 + t;
                int r = f >> 4, c = (f & 15) * 4;
                float4 v = *(const float4*)(Af + (size_t)(m0 + r) * lda + kbase + c);
                ushort4 o;
                o.x = f2bf(v.x); o.y = f2bf(v.y);
                o.z = f2bf(v.z); o.w = f2bf(v.w);
                *(ushort4*)(aL + r * 64 + c) = o;
            }
            __syncthreads();
#pragma unroll
            for (int ks = 0; ks < 2; ++ks) {
                const int cr = (ks * 4 + quad) * 8;
                bf16x8 av[4], bv[4];
#pragma unroll
                for (int mi = 0; mi < 4; ++mi)
                    av[mi] = *(const bf16x8*)(aL + (wm + mi * 16 + l15) * 64 + cr);
#pragma unroll
                for (int ni = 0; ni < 4; ++ni)
                    bv[ni] = *(const bf16x8*)(bL + (wn + ni * 16 + l15) * 64 + cr);
#pragma unroll
                for (int mi = 0; mi < 4; ++mi)
#pragma unroll
                    for (int ni = 0; ni < 4; ++ni)
                        acc[mi][ni] = __builtin_amdgcn_mfma_f32_16x16x32_bf16(
                            av[mi], bv[ni], acc[mi][ni], 0, 0, 0);
            }
            __syncthreads();
        }
    }

    // Epilogue. C/D layout: n = lane&15 (col), m = quad*4 + r (row) [m89/m91].
    if (EPI == 0) {            // +bias(fp32), transposed bf16 out [N][ldout]
#pragma unroll
        for (int ni = 0; ni < 4; ++ni) {
            int n = n0 + wn + ni * 16 + l15;
            float bvv = ((const float*)aux)[n];
            u16* ob = (u16*)outp + (size_t)n * ldout;
#pragma unroll
            for (int mi = 0; mi < 4; ++mi) {
                int m = m0 + wm + mi * 16 + quad * 4;
                ushort4 o;
                o.x = f2bf(acc[mi][ni][0] + bvv);
                o.y = f2bf(acc[mi][ni][1] + bvv);
                o.z = f2bf(acc[mi][ni][2] + bvv);
                o.w = f2bf(acc[mi][ni][3] + bvv);
                *(ushort4*)(ob + m) = o;
            }
        }
    } else if (EPI == 2) {     // fp32 partial, transposed [sk][NC][8192]
#pragma unroll
        for (int ni = 0; ni < 4; ++ni) {
            int n = n0 + wn + ni * 16 + l15;
            float* ob = (float*)outp + ((size_t)(sk * NC + n)) * 8192;
#pragma unroll
            for (int mi = 0; mi < 4; ++mi) {
                int m = m0 + wm + mi * 16 + quad * 4;
                float4 o;
                o.x = acc[mi][ni][0]; o.y = acc[mi][ni][1];
                o.z = acc[mi][ni][2]; o.w = acc[mi][ni][3];
                *(float4*)(ob + m) = o;
            }
        }
    } else if (EPI == 3) {     // z_new_T = bf16(0.9*acc + 0.1*z0T)
#pragma unroll
        for (int ni = 0; ni < 4; ++ni) {
            int n = n0 + wn + ni * 16 + l15;
            const u16* zrow = (const u16*)aux + (size_t)n * 8192;
            u16* ob = (u16*)outp + (size_t)n * ldout;
#pragma unroll
            for (int mi = 0; mi < 4; ++mi) {
                int m = m0 + wm + mi * 16 + quad * 4;
                ushort4 z0 = *(const ushort4*)(zrow + m);
                ushort4 o;
                o.x = f2bf(0.9f * acc[mi][ni][0] + 0.1f * bf2f(z0.x));
                o.y = f2bf(0.9f * acc[mi][ni][1] + 0.1f * bf2f(z0.y));
                o.z = f2bf(0.9f * acc[mi][ni][2] + 0.1f * bf2f(z0.z));
                o.w = f2bf(0.9f * acc[mi][ni][3] + 0.1f * bf2f(z0.w));
                *(ushort4*)(ob + m) = o;
            }
        }
    } else {                   // EPI==1: relu, normal bf16 out [M][ldout]
        u16* ob = (u16*)outp;
#pragma unroll
        for (int mi = 0; mi < 4; ++mi) {
            int m = m0 + wm + mi * 16 + quad * 4;
#pragma unroll
            for (int ni = 0; ni < 4; ++ni) {
                int n = n0 + wn + ni * 16 + l15;
#pragma unroll
                for (int r = 0; r < 4; ++r)
                    ob[(size_t)(m + r) * ldout + n] = f2bf(fmaxf(acc[mi][ni][r], 0.0f));
            }
        }
    }
}

// ---------------------------------------------------------------------------
// elementwise fp32 -> bf16 convert (grid-stride, float4/ushort4)
// ---------------------------------------------------------------------------
__global__ __launch_bounds__(256)
void cvt_f2b_k(const float* __restrict__ in, u16* __restrict__ out, long n4)
{
    long i = (long)blockIdx.x * 256 + threadIdx.x;
    long stride = (long)gridDim.x * 256;
    for (; i < n4; i += stride) {
        float4 v = ((const float4*)in)[i];
        ushort4 o;
        o.x = f2bf(v.x); o.y = f2bf(v.y); o.z = f2bf(v.z); o.w = f2bf(v.w);
        ((ushort4*)out)[i] = o;
    }
}

// ---------------------------------------------------------------------------
// weight transpose+convert: in fp32 [R][C] -> out bf16 [C][R]
// ---------------------------------------------------------------------------
__global__ __launch_bounds__(256)
void transpose_cvt_k(const float* __restrict__ in, u16* __restrict__ out,
                     int R, int C)
{
    __shared__ u16 tile[32][33];
    int tx = threadIdx.x, ty = threadIdx.y;
    int x = blockIdx.x * 32 + tx;
    int y0 = blockIdx.y * 32 + ty;
#pragma unroll
    for (int j = 0; j < 32; j += 8)
        tile[ty + j][tx] = f2bf(in[(size_t)(y0 + j) * C + x]);
    __syncthreads();
    int x2 = blockIdx.y * 32 + tx;
    int y2 = blockIdx.x * 32 + ty;
#pragma unroll
    for (int j = 0; j < 32; j += 8)
        out[(size_t)(y2 + j) * R + x2] = tile[tx][ty + j];
}

// ---------------------------------------------------------------------------
// combine_mlp: y[m][n] = relu(part[0][n][m] + part[1][n][m]) bf16
// part [2][512][8192] fp32; y [8192][512] bf16. 64x64 LDS-transpose tiles.
// ---------------------------------------------------------------------------
__global__ __launch_bounds__(256)
void combine_mlp_k(const float* __restrict__ part, u16* __restrict__ y)
{
    __shared__ u16 L[64][68];             // 68: 8B-aligned rows, de-conflicted
    const int t = threadIdx.x;
    const int mb = blockIdx.x * 64;       // m tile
    const int nb = blockIdx.y * 64;       // n tile
    const size_t S = (size_t)512 * 8192;
#pragma unroll
    for (int i = 0; i < 4; ++i) {
        int flat = i * 256 + t;
        int nl = flat >> 4;               // 0..63
        int mq = flat & 15;               // float4 column
        const float* p0 = part + (size_t)(nb + nl) * 8192 + mb + mq * 4;
        float4 a = *(const float4*)p0;
        float4 b = *(const float4*)(p0 + S);
        ushort4 o;
        o.x = f2bf(fmaxf(a.x + b.x, 0.f));
        o.y = f2bf(fmaxf(a.y + b.y, 0.f));
        o.z = f2bf(fmaxf(a.z + b.z, 0.f));
        o.w = f2bf(fmaxf(a.w + b.w, 0.f));
        *(ushort4*)&L[nl][mq * 4] = o;
    }
    __syncthreads();
#pragma unroll
    for (int i = 0; i < 4; ++i) {
        int flat = i * 256 + t;
        int ml  = flat >> 4;              // 0..63
        int nl4 = (flat & 15) * 4;
        ushort4 o;
        o.x = L[nl4 + 0][ml]; o.y = L[nl4 + 1][ml];
        o.z = L[nl4 + 2][ml]; o.w = L[nl4 + 3][ml];
        *(ushort4*)(y + (size_t)(mb + ml) * 512 + nb + nl4) = o;
    }
}

// ---------------------------------------------------------------------------
// combine_iter: zT = bf16(0.9 * sum_{s<4} part[s] + 0.1 * z0T), [256][8192]
// ---------------------------------------------------------------------------
__global__ __launch_bounds__(256)
void combine_iter_k(const float* __restrict__ part, const u16* __restrict__ z0T,
                    u16* __restrict__ zT)
{
    const size_t S = (size_t)256 * 8192;
    size_t e = ((size_t)blockIdx.x * 256 + threadIdx.x) * 4;
    float4 a = *(const float4*)(part + e);
    float4 b = *(const float4*)(part + S + e);
    float4 c = *(const float4*)(part + 2 * S + e);
    float4 d = *(const float4*)(part + 3 * S + e);
    ushort4 z0 = *(const ushort4*)(z0T + e);
    ushort4 o;
    o.x = f2bf(0.9f * (a.x + b.x + c.x + d.x) + 0.1f * bf2f(z0.x));
    o.y = f2bf(0.9f * (a.y + b.y + c.y + d.y) + 0.1f * bf2f(z0.y));
    o.z = f2bf(0.9f * (a.z + b.z + c.z + d.z) + 0.1f * bf2f(z0.z));
    o.w = f2bf(0.9f * (a.w + b.w + c.w + d.w) + 0.1f * bf2f(z0.w));
    *(ushort4*)(zT + e) = o;
}

// ---------------------------------------------------------------------------
// softmax over channels: zT [256][8192] bf16 -> out fp32 [8192][256]
// ---------------------------------------------------------------------------
__global__ __launch_bounds__(256)
void softmax_k(const u16* __restrict__ zT, float* __restrict__ out)
{
    __shared__ u16 L[64][260];
    const int t = threadIdx.x;
    const int m0 = blockIdx.x * 64;
    const int tx = t & 15, ty = t >> 4;
#pragma unroll
    for (int i = 0; i < 16; ++i) {
        int n = i * 16 + ty;
        ushort4 v = *(const ushort4*)(zT + (size_t)n * 8192 + m0 + tx * 4);
        L[tx * 4 + 0][n] = v.x; L[tx * 4 + 1][n] = v.y;
        L[tx * 4 + 2][n] = v.z; L[tx * 4 + 3][n] = v.w;
    }
    __syncthreads();
    const int wid = t >> 6, lane = t & 63;
    for (int r = 0; r < 16; ++r) {
        int mm = wid * 16 + r;
        ushort4 u = *(const ushort4*)(&L[mm][lane * 4]);
        float f0 = bf2f(u.x), f1 = bf2f(u.y), f2 = bf2f(u.z), f3 = bf2f(u.w);
        float mx = fmaxf(fmaxf(f0, f1), fmaxf(f2, f3));
#pragma unroll
        for (int off = 32; off > 0; off >>= 1) mx = fmaxf(mx, __shfl_xor(mx, off));
        float e0 = __expf(f0 - mx), e1 = __expf(f1 - mx);
        float e2 = __expf(f2 - mx), e3 = __expf(f3 - mx);
        float s = e0 + e1 + e2 + e3;
#pragma unroll
        for (int off = 32; off > 0; off >>= 1) s += __shfl_xor(s, off);
        float inv = 1.0f / s;
        float4 o;
        o.x = e0 * inv; o.y = e1 * inv; o.z = e2 * inv; o.w = e3 * inv;
        *(float4*)(out + (size_t)(m0 + mm) * 256 + lane * 4) = o;
    }
}

// ---------------------------------------------------------------------------
extern "C" void kernel_launch(void* const* d_in, const int* in_sizes, int n_in,
                              void* d_out, int out_size, void* d_ws, size_t ws_size,
                              hipStream_t stream)
{
    const float* features = (const float*)d_in[0];   // [8192][512]
    const float* fltr     = (const float*)d_in[1];   // [8192][8192]
    const float* W0       = (const float*)d_in[2];   // [512][512]
    const float* b0       = (const float*)d_in[3];   // [512]
    const float* W1       = (const float*)d_in[4];   // [512][512]
    const float* b1       = (const float*)d_in[5];   // [512]
    const float* Wo       = (const float*)d_in[6];   // [512][256]
    const float* bo       = (const float*)d_in[7];   // [256]

    dim3 tb(32, 8);

    // ---- base ws layout (72.6 MB) ----
    char* p = (char*)d_ws;
    u16* fB  = (u16*)p;  p += (size_t)8192 * 512 * 2;
    u16* W0T = (u16*)p;  p += (size_t)512 * 512 * 2;
    u16* W1T = (u16*)p;  p += (size_t)512 * 512 * 2;
    u16* WoT = (u16*)p;  p += (size_t)256 * 512 * 2;
    u16* z0T = (u16*)p;  p += (size_t)256 * 8192 * 2;
    u16* zA  = (u16*)p;  p += (size_t)256 * 8192 * 2;
    u16* zB  = (u16*)p;  p += (size_t)256 * 8192 * 2;
    u16* tT  = (u16*)p;  p += (size_t)512 * 8192 * 2;
    u16* y   = (u16*)p;  p += (size_t)8192 * 512 * 2;
    float* part = (float*)p; p += (size_t)2 * 512 * 8192 * 4;   // 33.5 MB
    size_t base_need = (size_t)(p - (char*)d_ws);
    u16* fltrB = (u16*)p;                             // +134.2 MB (full tier)
    size_t full_need = base_need + (size_t)8192 * 8192 * 2;

    if (ws_size >= full_need) {
        // ================= FULL TIER =================
        cvt_f2b_k<<<2048, 256, 0, stream>>>(fltr, fltrB, (long)8192 * 8192 / 4);
        cvt_f2b_k<<<512, 256, 0, stream>>>(features, fB, (long)8192 * 512 / 4);
        transpose_cvt_k<<<dim3(16, 16), tb, 0, stream>>>(W0, W0T, 512, 512);
        transpose_cvt_k<<<dim3(16, 16), tb, 0, stream>>>(W1, W1T, 512, 512);
        transpose_cvt_k<<<dim3(8, 16),  tb, 0, stream>>>(Wo, WoT, 512, 256);

        gemm_bt<0, 0><<<dim3(64, 4), 256, 0, stream>>>(fB, 512, W0T, 512, 8,
                                                       tT, b0, 8192, 0);
        gemm_bt<2, 0><<<dim3(64, 4, 2), 256, 0, stream>>>(fltrB, 8192, tT, 8192,
                                                          64, part, nullptr, 0, 512);
        combine_mlp_k<<<dim3(128, 8), 256, 0, stream>>>(part, y);
        gemm_bt<0, 0><<<dim3(64, 4), 256, 0, stream>>>(y, 512, W1T, 512, 8,
                                                       tT, b1, 8192, 0);
        gemm_bt<2, 0><<<dim3(64, 4, 2), 256, 0, stream>>>(fltrB, 8192, tT, 8192,
                                                          64, part, nullptr, 0, 512);
        combine_mlp_k<<<dim3(128, 8), 256, 0, stream>>>(part, y);
        gemm_bt<0, 0><<<dim3(64, 2), 256, 0, stream>>>(y, 512, WoT, 512, 8,
                                                       z0T, bo, 8192, 0);
        const u16* src = z0T;
        for (int it = 0; it < 10; ++it) {
            u16* dst = (it & 1) ? zB : zA;
            gemm_bt<2, 0><<<dim3(64, 2, 4), 256, 0, stream>>>(fltrB, 8192, src,
                                                              8192, 32, part,
                                                              nullptr, 0, 256);
            combine_iter_k<<<2048, 256, 0, stream>>>(part, z0T, dst);
            src = dst;
        }
        softmax_k<<<128, 256, 0, stream>>>(src, (float*)d_out);
    } else if (ws_size >= base_need) {
        // ================= MIDDLE TIER (fltr stays fp32) =================
        cvt_f2b_k<<<512, 256, 0, stream>>>(features, fB, (long)8192 * 512 / 4);
        transpose_cvt_k<<<dim3(16, 16), tb, 0, stream>>>(W0, W0T, 512, 512);
        transpose_cvt_k<<<dim3(16, 16), tb, 0, stream>>>(W1, W1T, 512, 512);
        transpose_cvt_k<<<dim3(8, 16),  tb, 0, stream>>>(Wo, WoT, 512, 256);

        gemm_bt<0, 0><<<dim3(64, 4), 256, 0, stream>>>(fB, 512, W0T, 512, 8,
                                                       tT, b0, 8192, 0);
        gemm_bt<2, 1><<<dim3(64, 4, 2), 256, 0, stream>>>(fltr, 8192, tT, 8192,
                                                          64, part, nullptr, 0, 512);
        combine_mlp_k<<<dim3(128, 8), 256, 0, stream>>>(part, y);
        gemm_bt<0, 0><<<dim3(64, 4), 256, 0, stream>>>(y, 512, W1T, 512, 8,
                                                       tT, b1, 8192, 0);
        gemm_bt<2, 1><<<dim3(64, 4, 2), 256, 0, stream>>>(fltr, 8192, tT, 8192,
                                                          64, part, nullptr, 0, 512);
        combine_mlp_k<<<dim3(128, 8), 256, 0, stream>>>(part, y);
        gemm_bt<0, 0><<<dim3(64, 2), 256, 0, stream>>>(y, 512, WoT, 512, 8,
                                                       z0T, bo, 8192, 0);
        const u16* src = z0T;
        for (int it = 0; it < 10; ++it) {
            u16* dst = (it & 1) ? zB : zA;
            gemm_bt<2, 1><<<dim3(64, 2, 4), 256, 0, stream>>>(fltr, 8192, src,
                                                              8192, 32, part,
                                                              nullptr, 0, 256);
            combine_iter_k<<<2048, 256, 0, stream>>>(part, z0T, dst);
            src = dst;
        }
        softmax_k<<<128, 256, 0, stream>>>(src, (float*)d_out);
    } else {
        // ================= FALLBACK (round-3 plan, 21.25 MB) =================
        char* w = (char*)d_ws;
        u16* fW0T = (u16*)w;  w += (size_t)512 * 512 * 2;
        u16* fW1T = (u16*)w;  w += (size_t)512 * 512 * 2;
        u16* fWoT = (u16*)w;  w += (size_t)256 * 512 * 2;
        u16* fz0T = (u16*)w;  w += (size_t)256 * 8192 * 2;
        char* rb = w;
        u16* ftT = (u16*)rb;
        u16* fy  = (u16*)(rb + (size_t)512 * 8192 * 2);
        u16* fzA = (u16*)rb;
        u16* fzB = (u16*)(rb + (size_t)256 * 8192 * 2);

        transpose_cvt_k<<<dim3(16, 16), tb, 0, stream>>>(W0, fW0T, 512, 512);
        transpose_cvt_k<<<dim3(16, 16), tb, 0, stream>>>(W1, fW1T, 512, 512);
        transpose_cvt_k<<<dim3(8, 16),  tb, 0, stream>>>(Wo, fWoT, 512, 256);
        gemm_bt<0, 1><<<dim3(64, 4), 256, 0, stream>>>(features, 512, fW0T, 512, 8,
                                                       ftT, b0, 8192, 0);
        gemm_bt<1, 1><<<dim3(64, 4), 256, 0, stream>>>(fltr, 8192, ftT, 8192, 128,
                                                       fy, nullptr, 512, 0);
        gemm_bt<0, 0><<<dim3(64, 4), 256, 0, stream>>>(fy, 512, fW1T, 512, 8,
                                                       ftT, b1, 8192, 0);
        gemm_bt<1, 1><<<dim3(64, 4), 256, 0, stream>>>(fltr, 8192, ftT, 8192, 128,
                                                       fy, nullptr, 512, 0);
        gemm_bt<0, 0><<<dim3(64, 2), 256, 0, stream>>>(fy, 512, fWoT, 512, 8,
                                                       fz0T, bo, 8192, 0);
        const u16* src = fz0T;
        for (int it = 0; it < 10; ++it) {
            u16* dst = (it & 1) ? fzB : fzA;
            gemm_bt<3, 1><<<dim3(64, 2), 256, 0, stream>>>(fltr, 8192, src, 8192,
                                                           128, dst, fz0T, 8192, 0);
            src = dst;
        }
        softmax_k<<<128, 256, 0, stream>>>(src, (float*)d_out);
    }
}

// Round 5
// 1214.271 us; speedup vs baseline: 4.2150x; 1.0449x over previous
//
#include <hip/hip_runtime.h>

typedef unsigned short u16;
typedef __attribute__((ext_vector_type(8))) short bf16x8;   // 8 bf16 = 4 VGPRs
typedef __attribute__((ext_vector_type(4))) float f32x4;

__device__ __forceinline__ float bf2f(u16 u) {
    union { unsigned i; float f; } v; v.i = ((unsigned)u) << 16; return v.f;
}
__device__ __forceinline__ u16 f2bf(float f) {
    union { float f; unsigned i; } v; v.f = f;
    unsigned r = v.i + 0x7FFFu + ((v.i >> 16) & 1u);   // RNE
    return (u16)(r >> 16);
}

#define GL2LDS(g, l) __builtin_amdgcn_global_load_lds(                         \
    (const __attribute__((address_space(1))) void*)(g),                        \
    (__attribute__((address_space(3))) void*)(l), 16, 0, 0)

// ---------------------------------------------------------------------------
// GEMM: C[M,N] = A[M,K] @ B[K,N], B given as B^T [N][K] bf16 (row-major, ldb).
// AFP32=1: A fp32, converted during staging (manual loads, no swizzle).
// AFP32=0: A bf16, GL2LDS width-16 staging, XOR-swizzled on the GLOBAL source
//          (LDS dest must stay lane-ordered — m104/m108); reads un-swizzle via
//          chunk^(row&7) -> ds_read_b128 lands 2 lanes/bank (free, m136).
// BM=BN=128, BK=64, 256 thr = 4 waves (2x2), wave tile 64x64 = 4x4 MFMA.
// blockIdx.z = split-K index (k0 = z * KB * 64).
// Epilogues: 0 = +bias (fp32 aux), transposed bf16 out [N][ldout]
//            1 = relu, normal bf16 out [M][ldout]
//            2 = fp32 partial, transposed [sk][NC][8192]
//            3 = appnp blend: out_T = bf16(0.9*acc + 0.1*aux bf16 [N][8192])
// ---------------------------------------------------------------------------
template<int EPI, int AFP32>
__global__ __launch_bounds__(256, 4)
void gemm_bt(const void* __restrict__ Ap, int lda,
             const u16* __restrict__ Bt, int ldb,
             int KB,                        // K-iterations (of 64) per split
             void* __restrict__ outp,
             const void* __restrict__ aux,  // fp32 bias (0) / bf16 z0T (3)
             int ldout, int NC)
{
    __shared__ u16 aL[128 * 64];           // 16 KB A tile (bf16)
    __shared__ u16 bL[128 * 64];           // 16 KB B^T tile (bf16)

    const int t = threadIdx.x;
    const int wid = t >> 6, lane = t & 63;
    const int quad = lane >> 4, l15 = lane & 15, l7 = lane & 7;
    const int m0 = blockIdx.x * 128, n0 = blockIdx.y * 128;
    const int sk = blockIdx.z;
    const int k0 = sk * KB * 64;           // elements

    f32x4 acc[4][4];
    const f32x4 z4 = {0.f, 0.f, 0.f, 0.f};
#pragma unroll
    for (int i = 0; i < 4; ++i)
#pragma unroll
        for (int j = 0; j < 4; ++j) acc[i][j] = z4;

    const int wm = (wid >> 1) * 64, wn = (wid & 1) * 64;

    if (AFP32 == 0) {
        // ---- GL2LDS staging, source-swizzled ----
        const char* pa[4]; const char* pb[4]; int lo[4];
#pragma unroll
        for (int i = 0; i < 4; ++i) {
            int flat = i * 4096 + wid * 1024 + lane * 16;  // byte in 16KB tile
            int row  = flat >> 7;                          // 128 B per row
            int csrc = ((flat >> 4) & 7) ^ (row & 7);      // swizzled 16B chunk
            pa[i] = (const char*)Ap + ((size_t)(m0 + row) * lda + k0) * 2 + csrc * 16;
            pb[i] = (const char*)Bt + ((size_t)(n0 + row) * ldb + k0) * 2 + csrc * 16;
            lo[i] = i * 4096 + wid * 1024;                 // wave-uniform base
        }
        for (int kb = 0; kb < KB; ++kb) {
#pragma unroll
            for (int i = 0; i < 4; ++i) GL2LDS(pa[i], (char*)aL + lo[i]);
#pragma unroll
            for (int i = 0; i < 4; ++i) GL2LDS(pb[i], (char*)bL + lo[i]);
#pragma unroll
            for (int i = 0; i < 4; ++i) { pa[i] += 128; pb[i] += 128; }
            __syncthreads();
#pragma unroll
            for (int ks = 0; ks < 2; ++ks) {
                const int cr = ((ks * 4 + quad) ^ l7) * 8; // un-swizzle on read
                bf16x8 av[4], bv[4];
#pragma unroll
                for (int mi = 0; mi < 4; ++mi)
                    av[mi] = *(const bf16x8*)(aL + (wm + mi * 16 + l15) * 64 + cr);
#pragma unroll
                for (int ni = 0; ni < 4; ++ni)
                    bv[ni] = *(const bf16x8*)(bL + (wn + ni * 16 + l15) * 64 + cr);
#pragma unroll
                for (int mi = 0; mi < 4; ++mi)
#pragma unroll
                    for (int ni = 0; ni < 4; ++ni)
                        acc[mi][ni] = __builtin_amdgcn_mfma_f32_16x16x32_bf16(
                            av[mi], bv[ni], acc[mi][ni], 0, 0, 0);
            }
            __syncthreads();
        }
    } else {
        // ---- manual staging (A fp32 -> bf16 cvt, B bf16), unswizzled ----
        for (int kb = 0; kb < KB; ++kb) {
            const int kbase = k0 + kb * 64;
#pragma unroll
            for (int i = 0; i < 4; ++i) {
                int flat = i * 4096 + t * 16;
                int row  = flat >> 7;
                int col  = (flat & 127) >> 1;
                bf16x8 v = *(const bf16x8*)(Bt + (size_t)(n0 + row) * ldb + kbase + col);
                *(bf16x8*)(bL + row * 64 + col) = v;
            }
            const float* Af = (const float*)Ap;
#pragma unroll
            for (int j = 0; j < 8; ++j) {
                int f = j * 256 + t;
                int r = f >> 4, c = (f & 15) * 4;
                float4 v = *(const float4*)(Af + (size_t)(m0 + r) * lda + kbase + c);
                ushort4 o;
                o.x = f2bf(v.x); o.y = f2bf(v.y);
                o.z = f2bf(v.z); o.w = f2bf(v.w);
                *(ushort4*)(aL + r * 64 + c) = o;
            }
            __syncthreads();
#pragma unroll
            for (int ks = 0; ks < 2; ++ks) {
                const int cr = (ks * 4 + quad) * 8;
                bf16x8 av[4], bv[4];
#pragma unroll
                for (int mi = 0; mi < 4; ++mi)
                    av[mi] = *(const bf16x8*)(aL + (wm + mi * 16 + l15) * 64 + cr);
#pragma unroll
                for (int ni = 0; ni < 4; ++ni)
                    bv[ni] = *(const bf16x8*)(bL + (wn + ni * 16 + l15) * 64 + cr);
#pragma unroll
                for (int mi = 0; mi < 4; ++mi)
#pragma unroll
                    for (int ni = 0; ni < 4; ++ni)
                        acc[mi][ni] = __builtin_amdgcn_mfma_f32_16x16x32_bf16(
                            av[mi], bv[ni], acc[mi][ni], 0, 0, 0);
            }
            __syncthreads();
        }
    }

    // Epilogue. C/D layout: n = lane&15 (col), m = quad*4 + r (row) [m89/m91].
    if (EPI == 0) {
#pragma unroll
        for (int ni = 0; ni < 4; ++ni) {
            int n = n0 + wn + ni * 16 + l15;
            float bvv = ((const float*)aux)[n];
            u16* ob = (u16*)outp + (size_t)n * ldout;
#pragma unroll
            for (int mi = 0; mi < 4; ++mi) {
                int m = m0 + wm + mi * 16 + quad * 4;
                ushort4 o;
                o.x = f2bf(acc[mi][ni][0] + bvv);
                o.y = f2bf(acc[mi][ni][1] + bvv);
                o.z = f2bf(acc[mi][ni][2] + bvv);
                o.w = f2bf(acc[mi][ni][3] + bvv);
                *(ushort4*)(ob + m) = o;
            }
        }
    } else if (EPI == 2) {     // fp32 partial, transposed [sk][NC][8192]
#pragma unroll
        for (int ni = 0; ni < 4; ++ni) {
            int n = n0 + wn + ni * 16 + l15;
            float* ob = (float*)outp + ((size_t)(sk * NC + n)) * 8192;
#pragma unroll
            for (int mi = 0; mi < 4; ++mi) {
                int m = m0 + wm + mi * 16 + quad * 4;
                float4 o;
                o.x = acc[mi][ni][0]; o.y = acc[mi][ni][1];
                o.z = acc[mi][ni][2]; o.w = acc[mi][ni][3];
                *(float4*)(ob + m) = o;
            }
        }
    } else if (EPI == 3) {     // z_new_T = bf16(0.9*acc + 0.1*z0T)
#pragma unroll
        for (int ni = 0; ni < 4; ++ni) {
            int n = n0 + wn + ni * 16 + l15;
            const u16* zrow = (const u16*)aux + (size_t)n * 8192;
            u16* ob = (u16*)outp + (size_t)n * ldout;
#pragma unroll
            for (int mi = 0; mi < 4; ++mi) {
                int m = m0 + wm + mi * 16 + quad * 4;
                ushort4 z0 = *(const ushort4*)(zrow + m);
                ushort4 o;
                o.x = f2bf(0.9f * acc[mi][ni][0] + 0.1f * bf2f(z0.x));
                o.y = f2bf(0.9f * acc[mi][ni][1] + 0.1f * bf2f(z0.y));
                o.z = f2bf(0.9f * acc[mi][ni][2] + 0.1f * bf2f(z0.z));
                o.w = f2bf(0.9f * acc[mi][ni][3] + 0.1f * bf2f(z0.w));
                *(ushort4*)(ob + m) = o;
            }
        }
    } else {                   // EPI==1: relu, normal bf16 out [M][ldout]
        u16* ob = (u16*)outp;
#pragma unroll
        for (int mi = 0; mi < 4; ++mi) {
            int m = m0 + wm + mi * 16 + quad * 4;
#pragma unroll
            for (int ni = 0; ni < 4; ++ni) {
                int n = n0 + wn + ni * 16 + l15;
#pragma unroll
                for (int r = 0; r < 4; ++r)
                    ob[(size_t)(m + r) * ldout + n] = f2bf(fmaxf(acc[mi][ni][r], 0.0f));
            }
        }
    }
}

// ---------------------------------------------------------------------------
__global__ __launch_bounds__(256)
void cvt_f2b_k(const float* __restrict__ in, u16* __restrict__ out, long n4)
{
    long i = (long)blockIdx.x * 256 + threadIdx.x;
    long stride = (long)gridDim.x * 256;
    for (; i < n4; i += stride) {
        float4 v = ((const float4*)in)[i];
        ushort4 o;
        o.x = f2bf(v.x); o.y = f2bf(v.y); o.z = f2bf(v.z); o.w = f2bf(v.w);
        ((ushort4*)out)[i] = o;
    }
}

// ---------------------------------------------------------------------------
__global__ __launch_bounds__(256)
void transpose_cvt_k(const float* __restrict__ in, u16* __restrict__ out,
                     int R, int C)
{
    __shared__ u16 tile[32][33];
    int tx = threadIdx.x, ty = threadIdx.y;
    int x = blockIdx.x * 32 + tx;
    int y0 = blockIdx.y * 32 + ty;
#pragma unroll
    for (int j = 0; j < 32; j += 8)
        tile[ty + j][tx] = f2bf(in[(size_t)(y0 + j) * C + x]);
    __syncthreads();
    int x2 = blockIdx.y * 32 + tx;
    int y2 = blockIdx.x * 32 + ty;
#pragma unroll
    for (int j = 0; j < 32; j += 8)
        out[(size_t)(y2 + j) * R + x2] = tile[tx][ty + j];
}

// ---------------------------------------------------------------------------
// combine_bias<S>: out[n][m] = bf16( sum_s part[s][n][m] + bias[n] )
// part [S][NROW][8192] fp32, out bf16 [NROW][8192]; elementwise, n-major.
// ---------------------------------------------------------------------------
template<int S>
__global__ __launch_bounds__(256)
void combine_bias_k(const float* __restrict__ part, const float* __restrict__ bias,
                    u16* __restrict__ out, long NROW)
{
    const size_t Sz = (size_t)NROW * 8192;
    size_t e = ((size_t)blockIdx.x * 256 + threadIdx.x) * 4;
    int n = (int)(e >> 13);
    float b = bias[n];
    float4 s = *(const float4*)(part + e);
#pragma unroll
    for (int i = 1; i < S; ++i) {
        float4 v = *(const float4*)(part + (size_t)i * Sz + e);
        s.x += v.x; s.y += v.y; s.z += v.z; s.w += v.w;
    }
    ushort4 o;
    o.x = f2bf(s.x + b); o.y = f2bf(s.y + b);
    o.z = f2bf(s.z + b); o.w = f2bf(s.w + b);
    *(ushort4*)(out + e) = o;
}

// ---------------------------------------------------------------------------
// combine_mlp<S>: y[m][n] = relu(sum_s part[s][n][m]) bf16
// part [S][512][8192] fp32; y [8192][512] bf16. 64x64 LDS-transpose tiles.
// ---------------------------------------------------------------------------
template<int S>
__global__ __launch_bounds__(256)
void combine_mlp_k(const float* __restrict__ part, u16* __restrict__ y)
{
    __shared__ u16 L[64][68];
    const int t = threadIdx.x;
    const int mb = blockIdx.x * 64;
    const int nb = blockIdx.y * 64;
    const size_t Sz = (size_t)512 * 8192;
#pragma unroll
    for (int i = 0; i < 4; ++i) {
        int flat = i * 256 + t;
        int nl = flat >> 4;
        int mq = flat & 15;
        const float* p0 = part + (size_t)(nb + nl) * 8192 + mb + mq * 4;
        float4 a = *(const float4*)p0;
#pragma unroll
        for (int s = 1; s < S; ++s) {
            float4 v = *(const float4*)(p0 + (size_t)s * Sz);
            a.x += v.x; a.y += v.y; a.z += v.z; a.w += v.w;
        }
        ushort4 o;
        o.x = f2bf(fmaxf(a.x, 0.f)); o.y = f2bf(fmaxf(a.y, 0.f));
        o.z = f2bf(fmaxf(a.z, 0.f)); o.w = f2bf(fmaxf(a.w, 0.f));
        *(ushort4*)&L[nl][mq * 4] = o;
    }
    __syncthreads();
#pragma unroll
    for (int i = 0; i < 4; ++i) {
        int flat = i * 256 + t;
        int ml  = flat >> 4;
        int nl4 = (flat & 15) * 4;
        ushort4 o;
        o.x = L[nl4 + 0][ml]; o.y = L[nl4 + 1][ml];
        o.z = L[nl4 + 2][ml]; o.w = L[nl4 + 3][ml];
        *(ushort4*)(y + (size_t)(mb + ml) * 512 + nb + nl4) = o;
    }
}

// ---------------------------------------------------------------------------
// combine_iter<S>: zT = bf16(0.9 * sum_s part[s] + 0.1 * z0T), [256][8192]
// ---------------------------------------------------------------------------
template<int S>
__global__ __launch_bounds__(256)
void combine_iter_k(const float* __restrict__ part, const u16* __restrict__ z0T,
                    u16* __restrict__ zT)
{
    const size_t Sz = (size_t)256 * 8192;
    size_t e = ((size_t)blockIdx.x * 256 + threadIdx.x) * 4;
    float4 a = *(const float4*)(part + e);
#pragma unroll
    for (int s = 1; s < S; ++s) {
        float4 v = *(const float4*)(part + (size_t)s * Sz + e);
        a.x += v.x; a.y += v.y; a.z += v.z; a.w += v.w;
    }
    ushort4 z0 = *(const ushort4*)(z0T + e);
    ushort4 o;
    o.x = f2bf(0.9f * a.x + 0.1f * bf2f(z0.x));
    o.y = f2bf(0.9f * a.y + 0.1f * bf2f(z0.y));
    o.z = f2bf(0.9f * a.z + 0.1f * bf2f(z0.z));
    o.w = f2bf(0.9f * a.w + 0.1f * bf2f(z0.w));
    *(ushort4*)(zT + e) = o;
}

// ---------------------------------------------------------------------------
__global__ __launch_bounds__(256)
void softmax_k(const u16* __restrict__ zT, float* __restrict__ out)
{
    __shared__ u16 L[64][260];
    const int t = threadIdx.x;
    const int m0 = blockIdx.x * 64;
    const int tx = t & 15, ty = t >> 4;
#pragma unroll
    for (int i = 0; i < 16; ++i) {
        int n = i * 16 + ty;
        ushort4 v = *(const ushort4*)(zT + (size_t)n * 8192 + m0 + tx * 4);
        L[tx * 4 + 0][n] = v.x; L[tx * 4 + 1][n] = v.y;
        L[tx * 4 + 2][n] = v.z; L[tx * 4 + 3][n] = v.w;
    }
    __syncthreads();
    const int wid = t >> 6, lane = t & 63;
    for (int r = 0; r < 16; ++r) {
        int mm = wid * 16 + r;
        ushort4 u = *(const ushort4*)(&L[mm][lane * 4]);
        float f0 = bf2f(u.x), f1 = bf2f(u.y), f2 = bf2f(u.z), f3 = bf2f(u.w);
        float mx = fmaxf(fmaxf(f0, f1), fmaxf(f2, f3));
#pragma unroll
        for (int off = 32; off > 0; off >>= 1) mx = fmaxf(mx, __shfl_xor(mx, off));
        float e0 = __expf(f0 - mx), e1 = __expf(f1 - mx);
        float e2 = __expf(f2 - mx), e3 = __expf(f3 - mx);
        float s = e0 + e1 + e2 + e3;
#pragma unroll
        for (int off = 32; off > 0; off >>= 1) s += __shfl_xor(s, off);
        float inv = 1.0f / s;
        float4 o;
        o.x = e0 * inv; o.y = e1 * inv; o.z = e2 * inv; o.w = e3 * inv;
        *(float4*)(out + (size_t)(m0 + mm) * 256 + lane * 4) = o;
    }
}

// ---------------------------------------------------------------------------
extern "C" void kernel_launch(void* const* d_in, const int* in_sizes, int n_in,
                              void* d_out, int out_size, void* d_ws, size_t ws_size,
                              hipStream_t stream)
{
    const float* features = (const float*)d_in[0];   // [8192][512]
    const float* fltr     = (const float*)d_in[1];   // [8192][8192]
    const float* W0       = (const float*)d_in[2];   // [512][512]
    const float* b0       = (const float*)d_in[3];   // [512]
    const float* W1       = (const float*)d_in[4];   // [512][512]
    const float* b1       = (const float*)d_in[5];   // [512]
    const float* Wo       = (const float*)d_in[6];   // [512][256]
    const float* bo       = (const float*)d_in[7];   // [256]

    dim3 tb(32, 8);

    // ---- base ws layout (~104.6 MB) ----
    char* p = (char*)d_ws;
    u16* fB  = (u16*)p;  p += (size_t)8192 * 512 * 2;
    u16* W0T = (u16*)p;  p += (size_t)512 * 512 * 2;
    u16* W1T = (u16*)p;  p += (size_t)512 * 512 * 2;
    u16* WoT = (u16*)p;  p += (size_t)256 * 512 * 2;
    u16* z0T = (u16*)p;  p += (size_t)256 * 8192 * 2;
    u16* zA  = (u16*)p;  p += (size_t)256 * 8192 * 2;
    u16* zB  = (u16*)p;  p += (size_t)256 * 8192 * 2;
    u16* tT  = (u16*)p;  p += (size_t)512 * 8192 * 2;
    u16* y   = (u16*)p;  p += (size_t)8192 * 512 * 2;
    float* part = (float*)p; p += (size_t)4 * 512 * 8192 * 4;   // 67.1 MB (max use)
    size_t base_need = (size_t)(p - (char*)d_ws);
    u16* fltrB = (u16*)p;                             // +134.2 MB (full tier)
    size_t full_need = base_need + (size_t)8192 * 8192 * 2;

    if (ws_size >= full_need) {
        // ================= FULL TIER =================
        cvt_f2b_k<<<2048, 256, 0, stream>>>(fltr, fltrB, (long)8192 * 8192 / 4);
        cvt_f2b_k<<<512, 256, 0, stream>>>(features, fB, (long)8192 * 512 / 4);
        transpose_cvt_k<<<dim3(16, 16), tb, 0, stream>>>(W0, W0T, 512, 512);
        transpose_cvt_k<<<dim3(16, 16), tb, 0, stream>>>(W1, W1T, 512, 512);
        transpose_cvt_k<<<dim3(8, 16),  tb, 0, stream>>>(Wo, WoT, 512, 256);

        // t0 = features @ W0 + b0   (sk=2, 512 blocks)
        gemm_bt<2, 0><<<dim3(64, 4, 2), 256, 0, stream>>>(fB, 512, W0T, 512, 4,
                                                          part, nullptr, 0, 512);
        combine_bias_k<2><<<4096, 256, 0, stream>>>(part, b0, tT, 512);
        // y1 = relu(fltr @ t0)      (sk=4, 1024 blocks)
        gemm_bt<2, 0><<<dim3(64, 4, 4), 256, 0, stream>>>(fltrB, 8192, tT, 8192,
                                                          32, part, nullptr, 0, 512);
        combine_mlp_k<4><<<dim3(128, 8), 256, 0, stream>>>(part, y);
        // t1 = y1 @ W1 + b1         (sk=2)
        gemm_bt<2, 0><<<dim3(64, 4, 2), 256, 0, stream>>>(y, 512, W1T, 512, 4,
                                                          part, nullptr, 0, 512);
        combine_bias_k<2><<<4096, 256, 0, stream>>>(part, b1, tT, 512);
        // y2 = relu(fltr @ t1)      (sk=4)
        gemm_bt<2, 0><<<dim3(64, 4, 4), 256, 0, stream>>>(fltrB, 8192, tT, 8192,
                                                          32, part, nullptr, 0, 512);
        combine_mlp_k<4><<<dim3(128, 8), 256, 0, stream>>>(part, y);
        // z0 = y2 @ Wo + bo         (sk=4, 512 blocks)
        gemm_bt<2, 0><<<dim3(64, 2, 4), 256, 0, stream>>>(y, 512, WoT, 512, 2,
                                                          part, nullptr, 0, 256);
        combine_bias_k<4><<<2048, 256, 0, stream>>>(part, bo, z0T, 256);
        // 10x: z <- 0.9*fltr@z + 0.1*z0   (sk=8, 1024 blocks)
        const u16* src = z0T;
        for (int it = 0; it < 10; ++it) {
            u16* dst = (it & 1) ? zB : zA;
            gemm_bt<2, 0><<<dim3(64, 2, 8), 256, 0, stream>>>(fltrB, 8192, src,
                                                              8192, 16, part,
                                                              nullptr, 0, 256);
            combine_iter_k<8><<<2048, 256, 0, stream>>>(part, z0T, dst);
            src = dst;
        }
        softmax_k<<<128, 256, 0, stream>>>(src, (float*)d_out);
    } else if (ws_size >= base_need) {
        // ================= MIDDLE TIER (fltr stays fp32) =================
        cvt_f2b_k<<<512, 256, 0, stream>>>(features, fB, (long)8192 * 512 / 4);
        transpose_cvt_k<<<dim3(16, 16), tb, 0, stream>>>(W0, W0T, 512, 512);
        transpose_cvt_k<<<dim3(16, 16), tb, 0, stream>>>(W1, W1T, 512, 512);
        transpose_cvt_k<<<dim3(8, 16),  tb, 0, stream>>>(Wo, WoT, 512, 256);

        gemm_bt<2, 0><<<dim3(64, 4, 2), 256, 0, stream>>>(fB, 512, W0T, 512, 4,
                                                          part, nullptr, 0, 512);
        combine_bias_k<2><<<4096, 256, 0, stream>>>(part, b0, tT, 512);
        gemm_bt<2, 1><<<dim3(64, 4, 4), 256, 0, stream>>>(fltr, 8192, tT, 8192,
                                                          32, part, nullptr, 0, 512);
        combine_mlp_k<4><<<dim3(128, 8), 256, 0, stream>>>(part, y);
        gemm_bt<2, 0><<<dim3(64, 4, 2), 256, 0, stream>>>(y, 512, W1T, 512, 4,
                                                          part, nullptr, 0, 512);
        combine_bias_k<2><<<4096, 256, 0, stream>>>(part, b1, tT, 512);
        gemm_bt<2, 1><<<dim3(64, 4, 4), 256, 0, stream>>>(fltr, 8192, tT, 8192,
                                                          32, part, nullptr, 0, 512);
        combine_mlp_k<4><<<dim3(128, 8), 256, 0, stream>>>(part, y);
        gemm_bt<2, 0><<<dim3(64, 2, 4), 256, 0, stream>>>(y, 512, WoT, 512, 2,
                                                          part, nullptr, 0, 256);
        combine_bias_k<4><<<2048, 256, 0, stream>>>(part, bo, z0T, 256);
        const u16* src = z0T;
        for (int it = 0; it < 10; ++it) {
            u16* dst = (it & 1) ? zB : zA;
            gemm_bt<2, 1><<<dim3(64, 2, 8), 256, 0, stream>>>(fltr, 8192, src,
                                                              8192, 16, part,
                                                              nullptr, 0, 256);
            combine_iter_k<8><<<2048, 256, 0, stream>>>(part, z0T, dst);
            src = dst;
        }
        softmax_k<<<128, 256, 0, stream>>>(src, (float*)d_out);
    } else {
        // ================= FALLBACK (round-3 plan, 21.25 MB) =================
        char* w = (char*)d_ws;
        u16* fW0T = (u16*)w;  w += (size_t)512 * 512 * 2;
        u16* fW1T = (u16*)w;  w += (size_t)512 * 512 * 2;
        u16* fWoT = (u16*)w;  w += (size_t)256 * 512 * 2;
        u16* fz0T = (u16*)w;  w += (size_t)256 * 8192 * 2;
        char* rb = w;
        u16* ftT = (u16*)rb;
        u16* fy  = (u16*)(rb + (size_t)512 * 8192 * 2);
        u16* fzA = (u16*)rb;
        u16* fzB = (u16*)(rb + (size_t)256 * 8192 * 2);

        transpose_cvt_k<<<dim3(16, 16), tb, 0, stream>>>(W0, fW0T, 512, 512);
        transpose_cvt_k<<<dim3(16, 16), tb, 0, stream>>>(W1, fW1T, 512, 512);
        transpose_cvt_k<<<dim3(8, 16),  tb, 0, stream>>>(Wo, fWoT, 512, 256);
        gemm_bt<0, 1><<<dim3(64, 4), 256, 0, stream>>>(features, 512, fW0T, 512, 8,
                                                       ftT, b0, 8192, 0);
        gemm_bt<1, 1><<<dim3(64, 4), 256, 0, stream>>>(fltr, 8192, ftT, 8192, 128,
                                                       fy, nullptr, 512, 0);
        gemm_bt<0, 0><<<dim3(64, 4), 256, 0, stream>>>(fy, 512, fW1T, 512, 8,
                                                       ftT, b1, 8192, 0);
        gemm_bt<1, 1><<<dim3(64, 4), 256, 0, stream>>>(fltr, 8192, ftT, 8192, 128,
                                                       fy, nullptr, 512, 0);
        gemm_bt<0, 0><<<dim3(64, 2), 256, 0, stream>>>(fy, 512, fWoT, 512, 8,
                                                       fz0T, bo, 8192, 0);
        const u16* src = fz0T;
        for (int it = 0; it < 10; ++it) {
            u16* dst = (it & 1) ? fzB : fzA;
            gemm_bt<3, 1><<<dim3(64, 2), 256, 0, stream>>>(fltr, 8192, src, 8192,
                                                           128, dst, fz0T, 8192, 0);
            src = dst;
        }
        softmax_k<<<128, 256, 0, stream>>>(src, (float*)d_out);
    }
}